// Round 6
// baseline (283.032 us; speedup 1.0000x reference)
//
#include <hip/hip_runtime.h>

#define EPSBN 1e-5f

typedef _Float16 f16;
typedef _Float16 f16x8 __attribute__((ext_vector_type(8)));
typedef _Float16 f16x4 __attribute__((ext_vector_type(4)));
typedef _Float16 f16x2 __attribute__((ext_vector_type(2)));
typedef float    f32x4 __attribute__((ext_vector_type(4)));

#define AS1 __attribute__((address_space(1)))
#define AS3 __attribute__((address_space(3)))

__device__ inline f16x8 hmax8(f16x8 a, f16x8 b) {
    f16x8 r;
    #pragma unroll
    for (int i = 0; i < 8; ++i) r[i] = a[i] > b[i] ? a[i] : b[i];
    return r;
}
__device__ inline f16x8 relu8(f16x8 v) {
    f16x8 r;
    #pragma unroll
    for (int i = 0; i < 8; ++i) r[i] = v[i] > (f16)0.f ? v[i] : (f16)0.f;
    return r;
}

// ---------------------------------------------------------------------------
// wprep: weights -> f16.
// region0 [0,32768): fc1 W in FRAGMENT order wfrag[s(8)][l(64)][otg(8)][k8(8)]
//   value = fc1w[o=otg*16+(l&15)][k = s*32 + (l>>4)*8 + k8]
// w1 [32768,40960) ; w2 as [tau][o][i] [40960,53248) ; w3 [53248,61440)
// ---------------------------------------------------------------------------
__global__ void wprep_kernel(const float* __restrict__ fc1w,
                             const float* __restrict__ w1,
                             const float* __restrict__ w2,
                             const float* __restrict__ w3,
                             f16* __restrict__ dst) {
    const int i = blockIdx.x * 256 + threadIdx.x;   // 61440 total
    float v;
    if (i < 32768) {
        const int k8 = i & 7, otg = (i >> 3) & 7, l = (i >> 6) & 63, s = i >> 12;
        const int n16l = l & 15, quadl = l >> 4;
        v = fc1w[(otg * 16 + n16l) * 256 + s * 32 + quadl * 8 + k8];
    }
    else if (i < 40960) v = w1[i - 32768];
    else if (i < 53248) {
        const int j = i - 40960, tau = j >> 12, rest = j & 4095;
        v = w2[rest * 3 + tau];
    } else              v = w3[i - 53248];
    dst[i] = (f16)v;
}

// ---------------------------------------------------------------------------
// fc1 v5: T14 reg-staged pipeline, lgkm-only barriers (vmcnt never drained
// in the main loop).
//   - DMA (v2/v4) stuck at ~11 GB/s/CU: cold-HBM global_load_lds completion
//     must drain at every consumer barrier.  Reg-staged loads survive raw
//     s_barrier + lgkmcnt(0) -> stage s+2 loads stay in flight across 2 iters.
//   - thread t stages (ch = t>>5, 8 pts = (t&31)*8): 2 float4 global (1 KB
//     contiguous per half-wave), cvt f16 in reg, ONE ds_write_b128
//     (conflict-free: half-wave writes 512 B contiguous).
//   - x LDS f16 [2][32][264] (33.8 KB) + W 64 KB (v4 layout, DMA'd once in
//     prologue) = 97.8 KB -> 1 block/CU, 1024 thr, 16 waves.
//   - frag reads: W ds_read_b128 x4, x ds_read_u16 x16 per wave-iter.
// ---------------------------------------------------------------------------
__global__ __launch_bounds__(1024, 4)
void fc1_mfma(const float* __restrict__ feat,   // [8][256][16384] f32
              const f16*   __restrict__ wfrag,  // [8][64][8][8] f16
              const float* __restrict__ bias,   // [128]
              f16*         __restrict__ xmap) { // [8][16384][128] f16
    __shared__ f16 wlds[32768];                  // 64 KB
    __shared__ union {
        f16 xb[2][32][264];                      // 33792 B (2 stage buffers)
        f16 epi[128][132];                       // 33792 B (epilogue staging)
    } u;

    const int tid  = threadIdx.x;
    const int wv   = tid >> 6;                   // 0..15
    const int lane = tid & 63;
    const int n16  = lane & 15, quad = lane >> 4;
    const int pw   = wv >> 1;                    // pt-tile 0..7 (32 pts)
    const int ow   = wv & 1;                     // o-half (64 outputs)
    const int img  = blockIdx.x & 7;             // XCD pin (same as loi)
    const int p0   = (blockIdx.x >> 3) << 8;     // 256-pt tile

    const float* fimg = feat + (((size_t)img) << 22);

    // staging map: thread -> (channel sch, 8 pts at sg*8); stage stride 2 MB
    const int sch = tid >> 5, sg = tid & 31;
    const float* sbase = fimg + (((size_t)sch) << 14) + p0 + sg * 8;

    f32x4 acc[2][4];
    #pragma unroll
    for (int ptg = 0; ptg < 2; ++ptg)
        #pragma unroll
        for (int t = 0; t < 4; ++t) acc[ptg][t] = (f32x4){0.f, 0.f, 0.f, 0.f};

    // ---- prologue: W DMA (4 chunks/wave) ----
    #pragma unroll
    for (int c4 = 0; c4 < 4; ++c4) {
        const int c = wv + 16 * c4;
        __builtin_amdgcn_global_load_lds((const AS1 void*)(wfrag + c * 512 + lane * 8),
                                         (AS3 void*)(wlds + c * 512), 16, 0, 0);
    }
    // stage 0 and 1 into regs; write stage 0
    float4 st[2][2];
    st[0][0] = *(const float4*)(sbase);
    st[0][1] = *(const float4*)(sbase + 4);
    st[1][0] = *(const float4*)(sbase + 524288);
    st[1][1] = *(const float4*)(sbase + 524292);
    {
        f16x8 h;
        #pragma unroll
        for (int i = 0; i < 4; ++i) { h[i] = (f16)st[0][0][i]; h[i + 4] = (f16)st[0][1][i]; }
        *(f16x8*)&u.xb[0][sch][sg * 8] = h;
    }
    asm volatile("s_waitcnt vmcnt(0)" ::: "memory");   // W + stage1 landed (prologue only)
    __syncthreads();

    // ---- main loop: 8 K-stages ----
    #pragma unroll
    for (int s = 0; s < 8; ++s) {
        // issue loads for stage s+2 (regs free: stage s was written last iter)
        if (s < 6) {
            st[s & 1][0] = *(const float4*)(sbase + (size_t)(s + 2) * 524288);
            st[s & 1][1] = *(const float4*)(sbase + (size_t)(s + 2) * 524288 + 4);
        }

        // W fragments (lgkm)
        f16x8 wf[4];
        #pragma unroll
        for (int t = 0; t < 4; ++t)
            wf[t] = *(const f16x8*)&wlds[((s * 64 + lane) * 8 + ow * 4 + t) * 8];

        // x fragments from u.xb[s&1]
        f16x8 xf[2];
        #pragma unroll
        for (int ptg = 0; ptg < 2; ++ptg) {
            const int pt = pw * 32 + ptg * 16 + n16;
            f16x8 xv;
            #pragma unroll
            for (int j = 0; j < 8; ++j) xv[j] = u.xb[s & 1][quad * 8 + j][pt];
            xf[ptg] = xv;
        }

        #pragma unroll
        for (int ptg = 0; ptg < 2; ++ptg)
            #pragma unroll
            for (int t = 0; t < 4; ++t)
                acc[ptg][t] = __builtin_amdgcn_mfma_f32_16x16x32_f16(wf[t], xf[ptg],
                                                                     acc[ptg][t], 0, 0, 0);

        // write stage s+1 (auto-wait is a COUNTED vmcnt: s+2 loads stay in flight)
        if (s < 7) {
            f16x8 h;
            #pragma unroll
            for (int i = 0; i < 4; ++i) {
                h[i]     = (f16)st[(s + 1) & 1][0][i];
                h[i + 4] = (f16)st[(s + 1) & 1][1][i];
            }
            *(f16x8*)&u.xb[(s + 1) & 1][sch][sg * 8] = h;

            __builtin_amdgcn_sched_barrier(0);
            asm volatile("s_waitcnt lgkmcnt(0)" ::: "memory");  // ds ops only; vmcnt untouched
            __builtin_amdgcn_sched_barrier(0);
            __builtin_amdgcn_s_barrier();
            __builtin_amdgcn_sched_barrier(0);
        }
    }

    // ---- epilogue: 2 passes of 128 rows through u.epi ----
    #pragma unroll
    for (int P = 0; P < 2; ++P) {
        __syncthreads();
        if ((pw >> 2) == P) {
            #pragma unroll
            for (int ptg = 0; ptg < 2; ++ptg) {
                const int rowl = (pw & 3) * 32 + ptg * 16 + n16;
                #pragma unroll
                for (int t = 0; t < 4; ++t) {
                    const int o = ow * 64 + t * 16 + quad * 4;
                    const float4 bq = *(const float4*)&bias[o];
                    f16x4 hv;
                    hv[0] = (f16)(acc[ptg][t][0] + bq.x);
                    hv[1] = (f16)(acc[ptg][t][1] + bq.y);
                    hv[2] = (f16)(acc[ptg][t][2] + bq.z);
                    hv[3] = (f16)(acc[ptg][t][3] + bq.w);
                    *(f16x4*)&u.epi[rowl][o] = hv;
                }
            }
        }
        __syncthreads();
        #pragma unroll
        for (int it = 0; it < 2; ++it) {
            const int idx = it * 1024 + tid;
            const int rowl = idx >> 4, seg = idx & 15;
            const float4 v = *(const float4*)&u.epi[rowl][seg * 8];
            *(float4*)&xmap[(((size_t)(img * 16384 + p0 + P * 128 + rowl)) << 7) + seg * 8] = v;
        }
    }
}

// ---------------------------------------------------------------------------
// loi: unchanged (63.5 us).  8 lines/block, XCD-pinned gathers, 16-B gathers
// (8 ch/lane), pool samples split across lane-halves + shfl_xor(16) max,
// conv1/conv2/conv3 MFMA, residual+relu+fc2.
// ---------------------------------------------------------------------------
__global__ __launch_bounds__(256)
void loi_kernel(const f16*   __restrict__ x,       // [8][16384][128] f16
                const float* __restrict__ lines,
                const f16*   __restrict__ wsp,
                const float* __restrict__ bn1g, const float* __restrict__ bn1b,
                const float* __restrict__ bn1m, const float* __restrict__ bn1v,
                const float* __restrict__ b1,
                const float* __restrict__ bn2g, const float* __restrict__ bn2b,
                const float* __restrict__ bn2m, const float* __restrict__ bn2v,
                const float* __restrict__ b2,
                const float* __restrict__ bn3g, const float* __restrict__ bn3b,
                const float* __restrict__ bn3m, const float* __restrict__ bn3v,
                const float* __restrict__ b3,
                const float* __restrict__ fc2w, const float* __restrict__ fc2b,
                float* __restrict__ out) {
    __shared__ f16 xp[64][136];                       // 17408 B
    __shared__ alignas(16) union {
        struct { int toff[256][4]; f16 twgt[256][4]; } tp;     // 6144 B
        struct { f16 h1[80][72]; f16 h2[64][72]; } cv;         // 20736 B
    } u;
    __shared__ f16 s1h[128], t1h[128];                // 512 B
    __shared__ float s2f[64], t2f[64], s3f[64], t3f[64], b1f[64], b2f[64];
    __shared__ float b3f[128];
    __shared__ float wsum[4][8];

    const f16* w1f16 = wsp + 32768;
    const f16* w2f16 = wsp + 40960;
    const f16* w3f16 = wsp + 53248;

    const int tid  = threadIdx.x;
    const int wv   = tid >> 6, lane = tid & 63;
    const int n16  = lane & 15, quad = lane >> 4;
    const int img  = blockIdx.x & 7;                  // XCD swizzle
    const int mblk = blockIdx.x >> 3;                 // 0..255 within image

    // ---- LUTs ----
    if (tid < 128) {
        const float s = bn1g[tid] * rsqrtf(bn1v[tid] + EPSBN);
        s1h[tid] = (f16)s; t1h[tid] = (f16)(bn1b[tid] - bn1m[tid] * s);
    }
    if (tid < 64) {
        const float s = bn2g[tid] * rsqrtf(bn2v[tid] + EPSBN);
        s2f[tid] = s; t2f[tid] = bn2b[tid] - bn2m[tid] * s;
        b1f[tid] = b1[tid];
    } else if (tid < 128) {
        const int c = tid - 64;
        const float s = bn3g[c] * rsqrtf(bn3v[c] + EPSBN);
        s3f[c] = s; t3f[c] = bn3b[c] - bn3m[c] * s;
        b2f[c] = b2[c];
    } else {
        b3f[tid - 128] = b3[tid - 128];
    }

    // ---- interp tuples: one per (line, pt) ----
    {
        const int li = tid >> 5, pt = tid & 31;
        const int gl = img * 2048 + mblk * 8 + li;
        const float4 ln = *(const float4*)&lines[gl * 4];
        const float lam = (float)pt * (1.0f / 31.0f);
        const float px = ln.x * lam + ln.z * (1.f - lam) - 0.5f;
        const float py = ln.y * lam + ln.w * (1.f - lam) - 0.5f;
        const float px0 = fminf(fmaxf(floorf(px), 0.f), 127.f);
        const float py0 = fminf(fmaxf(floorf(py), 0.f), 127.f);
        const float px1 = fminf(px0 + 1.f, 127.f);
        const float py1 = fminf(py0 + 1.f, 127.f);
        const int ix0 = (int)px0, iy0 = (int)py0;
        const int ix1 = (int)px1, iy1 = (int)py1;
        u.tp.toff[tid][0] = (((ix0 << 7) + iy0) << 7);
        u.tp.toff[tid][1] = (((ix1 << 7) + iy0) << 7);
        u.tp.toff[tid][2] = (((ix0 << 7) + iy1) << 7);
        u.tp.toff[tid][3] = (((ix1 << 7) + iy1) << 7);
        const float wx1 = px1 - px, wx0 = px - px0;
        const float wy1 = py1 - py, wy0 = py - py0;
        u.tp.twgt[tid][0] = (f16)(wx1 * wy1); u.tp.twgt[tid][1] = (f16)(wx0 * wy1);
        u.tp.twgt[tid][2] = (f16)(wx1 * wy0); u.tp.twgt[tid][3] = (f16)(wx0 * wy0);
    }
    __syncthreads();   // B1

    // ---- sampling + maxpool: 8 ch/lane (16 B gathers), 2 samples/lane-half,
    //      shfl_xor(16) final max ----
    {
        const int h  = lane >> 5;            // line parity within wave
        const int sh = (lane >> 4) & 1;      // which half of the 4 pool samples
        const int j  = lane & 15;            // 8-channel group
        const int li = wv * 2 + h;
        const f16* xbh = x + (((size_t)img) << 21) + 8 * j;
        #pragma unroll
        for (int t = 0; t < 8; ++t) {
            f16x8 m;
            #pragma unroll
            for (int q = 0; q < 8; ++q) m[q] = (f16)(-60000.f);
            #pragma unroll
            for (int ss = 0; ss < 2; ++ss) {
                const int combo = li * 32 + t * 4 + sh * 2 + ss;
                const int4  off = *(const int4*)&u.tp.toff[combo][0];
                const f16x4 tw  = *(const f16x4*)&u.tp.twgt[combo][0];
                const f16x8 g00 = *(const f16x8*)(xbh + off.x);
                const f16x8 g10 = *(const f16x8*)(xbh + off.y);
                const f16x8 g01 = *(const f16x8*)(xbh + off.z);
                const f16x8 g11 = *(const f16x8*)(xbh + off.w);
                f16x8 w0, w1v, w2v, w3v;
                #pragma unroll
                for (int q = 0; q < 8; ++q) {
                    w0[q] = tw[0]; w1v[q] = tw[1]; w2v[q] = tw[2]; w3v[q] = tw[3];
                }
                const f16x8 v = g00 * w0 + g10 * w1v + g01 * w2v + g11 * w3v;
                m = hmax8(m, v);
            }
            union { f16x8 v8; int i4[4]; } cv;
            cv.v8 = m;
            #pragma unroll
            for (int q = 0; q < 4; ++q) cv.i4[q] = __shfl_xor(cv.i4[q], 16, 64);
            m = hmax8(m, cv.v8);
            if (sh == 0) *(f16x8*)&xp[li * 8 + t][8 * j] = m;
        }
    }
    __syncthreads();   // B2 (tuples dead; xp ready)

    // ---- zero h1 guard rows ----
    {
        const int r = tid >> 4, seg = tid & 15;
        const int row = (r >> 1) * 10 + (r & 1) * 9;
        *(unsigned long long*)&u.cv.h1[row][seg * 4] = 0ull;
    }

    // ---- conv1 + fused bn1/relu (packed f16) ----
    {
        const int o_lane = wv * 16 + n16;
        f32x4 acc1[4];
        #pragma unroll
        for (int nt = 0; nt < 4; ++nt) acc1[nt] = (f32x4){0.f, 0.f, 0.f, 0.f};
        #pragma unroll
        for (int ks = 0; ks < 4; ++ks) {
            const int k = ks * 32 + quad * 8;
            const f16x8 a  = *(const f16x8*)&w1f16[o_lane * 128 + k];
            const f16x8 s8 = *(const f16x8*)&s1h[k];
            const f16x8 t8 = *(const f16x8*)&t1h[k];
            #pragma unroll
            for (int nt = 0; nt < 4; ++nt) {
                const f16x8 raw = *(const f16x8*)&xp[nt * 16 + n16][k];
                const f16x8 bf = relu8(raw * s8 + t8);
                acc1[nt] = __builtin_amdgcn_mfma_f32_16x16x32_f16(a, bf, acc1[nt], 0, 0, 0);
            }
        }
        #pragma unroll
        for (int nt = 0; nt < 4; ++nt) {
            const int n = nt * 16 + n16;
            const int nprow = (n >> 3) * 10 + (n & 7) + 1;
            #pragma unroll
            for (int r = 0; r < 4; ++r) {
                const int o = wv * 16 + quad * 4 + r;
                const float v = fmaxf((acc1[nt][r] + b1f[o]) * s2f[o] + t2f[o], 0.f);
                u.cv.h1[nprow][o] = (f16)v;
            }
        }
    }
    __syncthreads();   // B3

    // ---- conv2: 3 shifted [64x64] matmuls ----
    {
        const int o_lane = wv * 16 + n16;
        f32x4 acc2[4];
        #pragma unroll
        for (int nt = 0; nt < 4; ++nt) acc2[nt] = (f32x4){0.f, 0.f, 0.f, 0.f};
        #pragma unroll
        for (int d = 0; d < 3; ++d) {
            const f16* A2 = w2f16 + d * 4096;
            #pragma unroll
            for (int ks = 0; ks < 2; ++ks) {
                const int k = ks * 32 + quad * 8;
                const f16x8 a = *(const f16x8*)&A2[o_lane * 64 + k];
                #pragma unroll
                for (int nt = 0; nt < 4; ++nt) {
                    const int n = nt * 16 + n16;
                    const int row = (n >> 3) * 10 + (n & 7) + d;
                    const f16x8 bf = *(const f16x8*)&u.cv.h1[row][k];
                    acc2[nt] = __builtin_amdgcn_mfma_f32_16x16x32_f16(a, bf, acc2[nt], 0, 0, 0);
                }
            }
        }
        #pragma unroll
        for (int nt = 0; nt < 4; ++nt) {
            const int n = nt * 16 + n16;
            #pragma unroll
            for (int r = 0; r < 4; ++r) {
                const int o = wv * 16 + quad * 4 + r;
                const float v = fmaxf((acc2[nt][r] + b2f[o]) * s3f[o] + t3f[o], 0.f);
                u.cv.h2[n][o] = (f16)v;
            }
        }
    }
    __syncthreads();   // B4

    // ---- conv3 + residual + relu + fc2 ----
    {
        const int col = n16 & 7, obase = wv * 16 + quad * 4;
        float fcv[2][4];
        #pragma unroll
        for (int h = 0; h < 2; ++h)
            #pragma unroll
            for (int r = 0; r < 4; ++r)
                fcv[h][r] = fc2w[(h * 64 + obase + r) * 8 + col];

        f32x4 acc3[2][4];
        #pragma unroll
        for (int h = 0; h < 2; ++h)
            #pragma unroll
            for (int nt = 0; nt < 4; ++nt) acc3[h][nt] = (f32x4){0.f, 0.f, 0.f, 0.f};
        #pragma unroll
        for (int ks = 0; ks < 2; ++ks) {
            const int k = ks * 32 + quad * 8;
            const f16x8 a0 = *(const f16x8*)&w3f16[(wv * 16 + n16) * 64 + k];
            const f16x8 a1 = *(const f16x8*)&w3f16[(64 + wv * 16 + n16) * 64 + k];
            #pragma unroll
            for (int nt = 0; nt < 4; ++nt) {
                const f16x8 bf = *(const f16x8*)&u.cv.h2[nt * 16 + n16][k];
                acc3[0][nt] = __builtin_amdgcn_mfma_f32_16x16x32_f16(a0, bf, acc3[0][nt], 0, 0, 0);
                acc3[1][nt] = __builtin_amdgcn_mfma_f32_16x16x32_f16(a1, bf, acc3[1][nt], 0, 0, 0);
            }
        }
        float part[4] = {0.f, 0.f, 0.f, 0.f};
        #pragma unroll
        for (int h = 0; h < 2; ++h) {
            const float4 bq = *(const float4*)&b3f[h * 64 + obase];
            const float bqa[4] = {bq.x, bq.y, bq.z, bq.w};
            #pragma unroll
            for (int nt = 0; nt < 4; ++nt) {
                const int n = nt * 16 + n16;
                const f16x4 rx = *(const f16x4*)&xp[n][h * 64 + obase];
                float p = 0.f;
                #pragma unroll
                for (int r = 0; r < 4; ++r) {
                    float v = acc3[h][nt][r] + bqa[r] + (float)rx[r];
                    v = fmaxf(v, 0.f);
                    p += v * fcv[h][r];
                }
                part[nt] += p;
            }
        }
        #pragma unroll
        for (int off_i = 0; off_i < 5; ++off_i) {
            const int off = (int[]){1, 2, 4, 16, 32}[off_i];
            part[0] += __shfl_xor(part[0], off, 64);
            part[1] += __shfl_xor(part[1], off, 64);
            part[2] += __shfl_xor(part[2], off, 64);
            part[3] += __shfl_xor(part[3], off, 64);
        }
        if ((lane & 55) == 0) {          // lanes 0 and 8
            const int par = (lane >> 3) & 1;
            wsum[wv][0 + par] = part[0];
            wsum[wv][2 + par] = part[1];
            wsum[wv][4 + par] = part[2];
            wsum[wv][6 + par] = part[3];
        }
    }
    __syncthreads();   // B5

    if (tid < 8) {
        const float s = wsum[0][tid] + wsum[1][tid] + wsum[2][tid] + wsum[3][tid];
        out[img * 2048 + mblk * 8 + tid] = s + fc2b[0];
    }
}

// ---------------------------------------------------------------------------
extern "C" void kernel_launch(void* const* d_in, const int* in_sizes, int n_in,
                              void* d_out, int out_size, void* d_ws, size_t ws_size,
                              hipStream_t stream) {
    const float* feature = (const float*)d_in[0];
    const float* lines   = (const float*)d_in[1];
    const float* fc1_w   = (const float*)d_in[2];
    const float* fc1_b   = (const float*)d_in[3];
    const float* bn1g    = (const float*)d_in[4];
    const float* bn1b    = (const float*)d_in[5];
    const float* bn1m    = (const float*)d_in[6];
    const float* bn1v    = (const float*)d_in[7];
    const float* w1      = (const float*)d_in[8];
    const float* b1      = (const float*)d_in[9];
    const float* bn2g    = (const float*)d_in[10];
    const float* bn2b    = (const float*)d_in[11];
    const float* bn2m    = (const float*)d_in[12];
    const float* bn2v    = (const float*)d_in[13];
    const float* w2      = (const float*)d_in[14];
    const float* b2      = (const float*)d_in[15];
    const float* bn3g    = (const float*)d_in[16];
    const float* bn3b    = (const float*)d_in[17];
    const float* bn3m    = (const float*)d_in[18];
    const float* bn3v    = (const float*)d_in[19];
    const float* w3      = (const float*)d_in[20];
    const float* b3      = (const float*)d_in[21];
    const float* fc2w    = (const float*)d_in[22];
    const float* fc2b    = (const float*)d_in[23];

    f16* xmap = (f16*)d_ws;                                      // 32 MiB
    f16* wsp  = (f16*)((char*)d_ws + (size_t)32 * 1024 * 1024);  // 120 KiB

    wprep_kernel<<<240, 256, 0, stream>>>(fc1_w, w1, w2, w3, wsp);
    fc1_mfma<<<512, 1024, 0, stream>>>(feature, wsp, fc1_b, xmap);
    loi_kernel<<<2048, 256, 0, stream>>>(xmap, lines, wsp,
                                         bn1g, bn1b, bn1m, bn1v, b1,
                                         bn2g, bn2b, bn2m, bn2v, b2,
                                         bn3g, bn3b, bn3m, bn3v, b3,
                                         fc2w, fc2b, (float*)d_out);
}

// Round 7
// 278.137 us; speedup vs baseline: 1.0176x; 1.0176x over previous
//
#include <hip/hip_runtime.h>

#define EPSBN 1e-5f

typedef _Float16 f16;
typedef _Float16 f16x8 __attribute__((ext_vector_type(8)));
typedef _Float16 f16x4 __attribute__((ext_vector_type(4)));
typedef _Float16 f16x2 __attribute__((ext_vector_type(2)));
typedef float    f32x4 __attribute__((ext_vector_type(4)));

#define AS1 __attribute__((address_space(1)))
#define AS3 __attribute__((address_space(3)))

__device__ inline f16x8 hmax8(f16x8 a, f16x8 b) {
    f16x8 r;
    #pragma unroll
    for (int i = 0; i < 8; ++i) r[i] = a[i] > b[i] ? a[i] : b[i];
    return r;
}
__device__ inline f16x8 relu8(f16x8 v) {
    f16x8 r;
    #pragma unroll
    for (int i = 0; i < 8; ++i) r[i] = v[i] > (f16)0.f ? v[i] : (f16)0.f;
    return r;
}

// ---------------------------------------------------------------------------
// wprep: weights -> f16.
// region0 [0,32768): fc1 W, LANE-INTERLEAVED fragment order (conflict-free
// ds_read_b128: lane stride 16 B):
//   wfrag[s(8)][ow(2)][t(4)][lane(64)][k8(8)]
//   value = fc1w[o = ow*64 + t*16 + (lane&15)][k = s*32 + (lane>>4)*8 + k8]
// w1 [32768,40960) ; w2 as [tau][o][i] [40960,53248) ; w3 [53248,61440)
// ---------------------------------------------------------------------------
__global__ void wprep_kernel(const float* __restrict__ fc1w,
                             const float* __restrict__ w1,
                             const float* __restrict__ w2,
                             const float* __restrict__ w3,
                             f16* __restrict__ dst) {
    const int i = blockIdx.x * 256 + threadIdx.x;   // 61440 total
    float v;
    if (i < 32768) {
        const int k8   = i & 7;
        const int lane = (i >> 3) & 63;
        const int t    = (i >> 9) & 3;
        const int ow   = (i >> 11) & 1;
        const int s    = (i >> 12) & 7;
        const int n16l = lane & 15, quadl = lane >> 4;
        v = fc1w[(ow * 64 + t * 16 + n16l) * 256 + s * 32 + quadl * 8 + k8];
    }
    else if (i < 40960) v = w1[i - 32768];
    else if (i < 53248) {
        const int j = i - 40960, tau = j >> 12, rest = j & 4095;
        v = w2[rest * 3 + tau];
    } else              v = w3[i - 53248];
    dst[i] = (f16)v;
}

// ---------------------------------------------------------------------------
// fc1 v6: conflict-free LDS fragment layouts (the real fix).
// v2/v4/v5 all ~63-66 us regardless of staging mechanism: iteration period
// 9300 cy was LDS-pipe serialization, not HBM.  v4/v5's W reads had lane
// stride 128 B == 0 mod 32 banks -> all 64 lanes on one 4-bank group (8x the
// minimum phases) ~= 6-7 kcy/iter; x-frags were 16 scalar ds_read_u16.
// v6 (same v5 reg-staged skeleton, lgkm-only barriers):
//   - W: wlds[frag][lane][8f16] -> lane stride 16 B, conflict-free b128.
//   - x: xb[pt][32ch] rows (64 B), col-group XOR swizzle (pt>>1)&3; staging
//     thread = (pt, 8 ch): 8 coalesced 256 B loads, ONE ds_write_b128;
//     B-fragment = ONE swizzled ds_read_b128 (was 16 u16 reads).
// LDS: W 64 KB + xb 32 KB (union epi 17 KB) = 96 KB -> 1 blk/CU, 16 waves.
// ---------------------------------------------------------------------------
__global__ __launch_bounds__(1024, 4)
void fc1_mfma(const float* __restrict__ feat,   // [8][256][16384] f32
              const f16*   __restrict__ wfrag,  // [8][2][4][64][8] f16
              const float* __restrict__ bias,   // [128]
              f16*         __restrict__ xmap) { // [8][16384][128] f16
    __shared__ f16 wlds[32768];                  // 64 KB
    __shared__ union {
        f16 xb[2][256][32];                      // 32768 B (2 stage buffers)
        f16 epi[64][136];                        // 17408 B (epilogue staging)
    } u;

    const int tid  = threadIdx.x;
    const int wv   = tid >> 6;                   // 0..15
    const int lane = tid & 63;
    const int n16  = lane & 15, quad = lane >> 4;
    const int pw   = wv >> 1;                    // pt-tile 0..7 (32 pts)
    const int ow   = wv & 1;                     // o-half (64 outputs)
    const int img  = blockIdx.x & 7;             // XCD pin (same as loi)
    const int p0   = (blockIdx.x >> 3) << 8;     // 256-pt tile

    const float* fimg = feat + (((size_t)img) << 22);

    // staging map: thread -> (pt = tid&255, 8 channels at chgrp*8)
    const int spt = tid & 255, chgrp = tid >> 8;
    const float* sbase = fimg + (((size_t)(chgrp * 8)) << 14) + p0 + spt;
    const int swcol = (chgrp ^ ((spt >> 1) & 3)) << 3;   // swizzled f16 col

    f32x4 acc[2][4];
    #pragma unroll
    for (int ptg = 0; ptg < 2; ++ptg)
        #pragma unroll
        for (int t = 0; t < 4; ++t) acc[ptg][t] = (f32x4){0.f, 0.f, 0.f, 0.f};

    // ---- prologue: W DMA (4 linear 1 KB chunks/wave) ----
    #pragma unroll
    for (int c4 = 0; c4 < 4; ++c4) {
        const int c = wv + 16 * c4;
        __builtin_amdgcn_global_load_lds((const AS1 void*)(wfrag + c * 512 + lane * 8),
                                         (AS3 void*)(wlds + c * 512), 16, 0, 0);
    }
    // stage 0 and 1 into regs (8 dwords each); write stage 0
    float st[2][8];
    #pragma unroll
    for (int c = 0; c < 8; ++c) {
        st[0][c] = sbase[(size_t)c << 14];
        st[1][c] = sbase[524288 + ((size_t)c << 14)];
    }
    {
        f16x8 h;
        #pragma unroll
        for (int c = 0; c < 8; ++c) h[c] = (f16)st[0][c];
        *(f16x8*)&u.xb[0][spt][swcol] = h;
    }
    asm volatile("s_waitcnt vmcnt(0)" ::: "memory");   // W + stage1 landed (prologue only)
    __syncthreads();

    // ---- main loop: 8 K-stages ----
    #pragma unroll
    for (int s = 0; s < 8; ++s) {
        // issue loads for stage s+2 (regs free: stage s was written last iter)
        if (s < 6) {
            #pragma unroll
            for (int c = 0; c < 8; ++c)
                st[s & 1][c] = sbase[(size_t)(s + 2) * 524288 + ((size_t)c << 14)];
        }

        // W fragments: lane-interleaved, conflict-free b128
        f16x8 wf[4];
        #pragma unroll
        for (int t = 0; t < 4; ++t)
            wf[t] = *(const f16x8*)&wlds[((((s * 2 + ow) * 4 + t) * 64) + lane) * 8];

        // x fragments: one swizzled b128 per ptg
        f16x8 xf[2];
        #pragma unroll
        for (int ptg = 0; ptg < 2; ++ptg) {
            const int pt = pw * 32 + ptg * 16 + n16;
            xf[ptg] = *(const f16x8*)&u.xb[s & 1][pt][(quad ^ ((pt >> 1) & 3)) << 3];
        }

        #pragma unroll
        for (int ptg = 0; ptg < 2; ++ptg)
            #pragma unroll
            for (int t = 0; t < 4; ++t)
                acc[ptg][t] = __builtin_amdgcn_mfma_f32_16x16x32_f16(wf[t], xf[ptg],
                                                                     acc[ptg][t], 0, 0, 0);

        // write stage s+1 (auto-wait is a COUNTED vmcnt: s+2 loads stay in flight)
        if (s < 7) {
            f16x8 h;
            #pragma unroll
            for (int c = 0; c < 8; ++c) h[c] = (f16)st[(s + 1) & 1][c];
            *(f16x8*)&u.xb[(s + 1) & 1][spt][swcol] = h;

            __builtin_amdgcn_sched_barrier(0);
            asm volatile("s_waitcnt lgkmcnt(0)" ::: "memory");  // ds only; vmcnt untouched
            __builtin_amdgcn_sched_barrier(0);
            __builtin_amdgcn_s_barrier();
            __builtin_amdgcn_sched_barrier(0);
        }
    }

    // ---- epilogue: 4 passes of 64 rows through u.epi ----
    #pragma unroll
    for (int P = 0; P < 4; ++P) {
        __syncthreads();
        if ((pw >> 1) == P) {
            #pragma unroll
            for (int ptg = 0; ptg < 2; ++ptg) {
                const int rowl = (pw & 1) * 32 + ptg * 16 + n16;
                #pragma unroll
                for (int t = 0; t < 4; ++t) {
                    const int o = ow * 64 + t * 16 + quad * 4;
                    const float4 bq = *(const float4*)&bias[o];
                    f16x4 hv;
                    hv[0] = (f16)(acc[ptg][t][0] + bq.x);
                    hv[1] = (f16)(acc[ptg][t][1] + bq.y);
                    hv[2] = (f16)(acc[ptg][t][2] + bq.z);
                    hv[3] = (f16)(acc[ptg][t][3] + bq.w);
                    *(f16x4*)&u.epi[rowl][o] = hv;
                }
            }
        }
        __syncthreads();
        {
            const int rowl = tid >> 4, seg = tid & 15;
            const float4 v = *(const float4*)&u.epi[rowl][seg * 8];
            *(float4*)&xmap[(((size_t)(img * 16384 + p0 + P * 64 + rowl)) << 7) + seg * 8] = v;
        }
    }
}

// ---------------------------------------------------------------------------
// loi: unchanged (63.5 us).  8 lines/block, XCD-pinned gathers, 16-B gathers
// (8 ch/lane), pool samples split across lane-halves + shfl_xor(16) max,
// conv1/conv2/conv3 MFMA, residual+relu+fc2.
// ---------------------------------------------------------------------------
__global__ __launch_bounds__(256)
void loi_kernel(const f16*   __restrict__ x,       // [8][16384][128] f16
                const float* __restrict__ lines,
                const f16*   __restrict__ wsp,
                const float* __restrict__ bn1g, const float* __restrict__ bn1b,
                const float* __restrict__ bn1m, const float* __restrict__ bn1v,
                const float* __restrict__ b1,
                const float* __restrict__ bn2g, const float* __restrict__ bn2b,
                const float* __restrict__ bn2m, const float* __restrict__ bn2v,
                const float* __restrict__ b2,
                const float* __restrict__ bn3g, const float* __restrict__ bn3b,
                const float* __restrict__ bn3m, const float* __restrict__ bn3v,
                const float* __restrict__ b3,
                const float* __restrict__ fc2w, const float* __restrict__ fc2b,
                float* __restrict__ out) {
    __shared__ f16 xp[64][136];                       // 17408 B
    __shared__ alignas(16) union {
        struct { int toff[256][4]; f16 twgt[256][4]; } tp;     // 6144 B
        struct { f16 h1[80][72]; f16 h2[64][72]; } cv;         // 20736 B
    } u;
    __shared__ f16 s1h[128], t1h[128];                // 512 B
    __shared__ float s2f[64], t2f[64], s3f[64], t3f[64], b1f[64], b2f[64];
    __shared__ float b3f[128];
    __shared__ float wsum[4][8];

    const f16* w1f16 = wsp + 32768;
    const f16* w2f16 = wsp + 40960;
    const f16* w3f16 = wsp + 53248;

    const int tid  = threadIdx.x;
    const int wv   = tid >> 6, lane = tid & 63;
    const int n16  = lane & 15, quad = lane >> 4;
    const int img  = blockIdx.x & 7;                  // XCD swizzle
    const int mblk = blockIdx.x >> 3;                 // 0..255 within image

    // ---- LUTs ----
    if (tid < 128) {
        const float s = bn1g[tid] * rsqrtf(bn1v[tid] + EPSBN);
        s1h[tid] = (f16)s; t1h[tid] = (f16)(bn1b[tid] - bn1m[tid] * s);
    }
    if (tid < 64) {
        const float s = bn2g[tid] * rsqrtf(bn2v[tid] + EPSBN);
        s2f[tid] = s; t2f[tid] = bn2b[tid] - bn2m[tid] * s;
        b1f[tid] = b1[tid];
    } else if (tid < 128) {
        const int c = tid - 64;
        const float s = bn3g[c] * rsqrtf(bn3v[c] + EPSBN);
        s3f[c] = s; t3f[c] = bn3b[c] - bn3m[c] * s;
        b2f[c] = b2[c];
    } else {
        b3f[tid - 128] = b3[tid - 128];
    }

    // ---- interp tuples: one per (line, pt) ----
    {
        const int li = tid >> 5, pt = tid & 31;
        const int gl = img * 2048 + mblk * 8 + li;
        const float4 ln = *(const float4*)&lines[gl * 4];
        const float lam = (float)pt * (1.0f / 31.0f);
        const float px = ln.x * lam + ln.z * (1.f - lam) - 0.5f;
        const float py = ln.y * lam + ln.w * (1.f - lam) - 0.5f;
        const float px0 = fminf(fmaxf(floorf(px), 0.f), 127.f);
        const float py0 = fminf(fmaxf(floorf(py), 0.f), 127.f);
        const float px1 = fminf(px0 + 1.f, 127.f);
        const float py1 = fminf(py0 + 1.f, 127.f);
        const int ix0 = (int)px0, iy0 = (int)py0;
        const int ix1 = (int)px1, iy1 = (int)py1;
        u.tp.toff[tid][0] = (((ix0 << 7) + iy0) << 7);
        u.tp.toff[tid][1] = (((ix1 << 7) + iy0) << 7);
        u.tp.toff[tid][2] = (((ix0 << 7) + iy1) << 7);
        u.tp.toff[tid][3] = (((ix1 << 7) + iy1) << 7);
        const float wx1 = px1 - px, wx0 = px - px0;
        const float wy1 = py1 - py, wy0 = py - py0;
        u.tp.twgt[tid][0] = (f16)(wx1 * wy1); u.tp.twgt[tid][1] = (f16)(wx0 * wy1);
        u.tp.twgt[tid][2] = (f16)(wx1 * wy0); u.tp.twgt[tid][3] = (f16)(wx0 * wy0);
    }
    __syncthreads();   // B1

    // ---- sampling + maxpool: 8 ch/lane (16 B gathers), 2 samples/lane-half,
    //      shfl_xor(16) final max ----
    {
        const int h  = lane >> 5;            // line parity within wave
        const int sh = (lane >> 4) & 1;      // which half of the 4 pool samples
        const int j  = lane & 15;            // 8-channel group
        const int li = wv * 2 + h;
        const f16* xbh = x + (((size_t)img) << 21) + 8 * j;
        #pragma unroll
        for (int t = 0; t < 8; ++t) {
            f16x8 m;
            #pragma unroll
            for (int q = 0; q < 8; ++q) m[q] = (f16)(-60000.f);
            #pragma unroll
            for (int ss = 0; ss < 2; ++ss) {
                const int combo = li * 32 + t * 4 + sh * 2 + ss;
                const int4  off = *(const int4*)&u.tp.toff[combo][0];
                const f16x4 tw  = *(const f16x4*)&u.tp.twgt[combo][0];
                const f16x8 g00 = *(const f16x8*)(xbh + off.x);
                const f16x8 g10 = *(const f16x8*)(xbh + off.y);
                const f16x8 g01 = *(const f16x8*)(xbh + off.z);
                const f16x8 g11 = *(const f16x8*)(xbh + off.w);
                f16x8 w0, w1v, w2v, w3v;
                #pragma unroll
                for (int q = 0; q < 8; ++q) {
                    w0[q] = tw[0]; w1v[q] = tw[1]; w2v[q] = tw[2]; w3v[q] = tw[3];
                }
                const f16x8 v = g00 * w0 + g10 * w1v + g01 * w2v + g11 * w3v;
                m = hmax8(m, v);
            }
            union { f16x8 v8; int i4[4]; } cv;
            cv.v8 = m;
            #pragma unroll
            for (int q = 0; q < 4; ++q) cv.i4[q] = __shfl_xor(cv.i4[q], 16, 64);
            m = hmax8(m, cv.v8);
            if (sh == 0) *(f16x8*)&xp[li * 8 + t][8 * j] = m;
        }
    }
    __syncthreads();   // B2 (tuples dead; xp ready)

    // ---- zero h1 guard rows ----
    {
        const int r = tid >> 4, seg = tid & 15;
        const int row = (r >> 1) * 10 + (r & 1) * 9;
        *(unsigned long long*)&u.cv.h1[row][seg * 4] = 0ull;
    }

    // ---- conv1 + fused bn1/relu (packed f16) ----
    {
        const int o_lane = wv * 16 + n16;
        f32x4 acc1[4];
        #pragma unroll
        for (int nt = 0; nt < 4; ++nt) acc1[nt] = (f32x4){0.f, 0.f, 0.f, 0.f};
        #pragma unroll
        for (int ks = 0; ks < 4; ++ks) {
            const int k = ks * 32 + quad * 8;
            const f16x8 a  = *(const f16x8*)&w1f16[o_lane * 128 + k];
            const f16x8 s8 = *(const f16x8*)&s1h[k];
            const f16x8 t8 = *(const f16x8*)&t1h[k];
            #pragma unroll
            for (int nt = 0; nt < 4; ++nt) {
                const f16x8 raw = *(const f16x8*)&xp[nt * 16 + n16][k];
                const f16x8 bf = relu8(raw * s8 + t8);
                acc1[nt] = __builtin_amdgcn_mfma_f32_16x16x32_f16(a, bf, acc1[nt], 0, 0, 0);
            }
        }
        #pragma unroll
        for (int nt = 0; nt < 4; ++nt) {
            const int n = nt * 16 + n16;
            const int nprow = (n >> 3) * 10 + (n & 7) + 1;
            #pragma unroll
            for (int r = 0; r < 4; ++r) {
                const int o = wv * 16 + quad * 4 + r;
                const float v = fmaxf((acc1[nt][r] + b1f[o]) * s2f[o] + t2f[o], 0.f);
                u.cv.h1[nprow][o] = (f16)v;
            }
        }
    }
    __syncthreads();   // B3

    // ---- conv2: 3 shifted [64x64] matmuls ----
    {
        const int o_lane = wv * 16 + n16;
        f32x4 acc2[4];
        #pragma unroll
        for (int nt = 0; nt < 4; ++nt) acc2[nt] = (f32x4){0.f, 0.f, 0.f, 0.f};
        #pragma unroll
        for (int d = 0; d < 3; ++d) {
            const f16* A2 = w2f16 + d * 4096;
            #pragma unroll
            for (int ks = 0; ks < 2; ++ks) {
                const int k = ks * 32 + quad * 8;
                const f16x8 a = *(const f16x8*)&A2[o_lane * 64 + k];
                #pragma unroll
                for (int nt = 0; nt < 4; ++nt) {
                    const int n = nt * 16 + n16;
                    const int row = (n >> 3) * 10 + (n & 7) + d;
                    const f16x8 bf = *(const f16x8*)&u.cv.h1[row][k];
                    acc2[nt] = __builtin_amdgcn_mfma_f32_16x16x32_f16(a, bf, acc2[nt], 0, 0, 0);
                }
            }
        }
        #pragma unroll
        for (int nt = 0; nt < 4; ++nt) {
            const int n = nt * 16 + n16;
            #pragma unroll
            for (int r = 0; r < 4; ++r) {
                const int o = wv * 16 + quad * 4 + r;
                const float v = fmaxf((acc2[nt][r] + b2f[o]) * s3f[o] + t3f[o], 0.f);
                u.cv.h2[n][o] = (f16)v;
            }
        }
    }
    __syncthreads();   // B4

    // ---- conv3 + residual + relu + fc2 ----
    {
        const int col = n16 & 7, obase = wv * 16 + quad * 4;
        float fcv[2][4];
        #pragma unroll
        for (int h = 0; h < 2; ++h)
            #pragma unroll
            for (int r = 0; r < 4; ++r)
                fcv[h][r] = fc2w[(h * 64 + obase + r) * 8 + col];

        f32x4 acc3[2][4];
        #pragma unroll
        for (int h = 0; h < 2; ++h)
            #pragma unroll
            for (int nt = 0; nt < 4; ++nt) acc3[h][nt] = (f32x4){0.f, 0.f, 0.f, 0.f};
        #pragma unroll
        for (int ks = 0; ks < 2; ++ks) {
            const int k = ks * 32 + quad * 8;
            const f16x8 a0 = *(const f16x8*)&w3f16[(wv * 16 + n16) * 64 + k];
            const f16x8 a1 = *(const f16x8*)&w3f16[(64 + wv * 16 + n16) * 64 + k];
            #pragma unroll
            for (int nt = 0; nt < 4; ++nt) {
                const f16x8 bf = *(const f16x8*)&u.cv.h2[nt * 16 + n16][k];
                acc3[0][nt] = __builtin_amdgcn_mfma_f32_16x16x32_f16(a0, bf, acc3[0][nt], 0, 0, 0);
                acc3[1][nt] = __builtin_amdgcn_mfma_f32_16x16x32_f16(a1, bf, acc3[1][nt], 0, 0, 0);
            }
        }
        float part[4] = {0.f, 0.f, 0.f, 0.f};
        #pragma unroll
        for (int h = 0; h < 2; ++h) {
            const float4 bq = *(const float4*)&b3f[h * 64 + obase];
            const float bqa[4] = {bq.x, bq.y, bq.z, bq.w};
            #pragma unroll
            for (int nt = 0; nt < 4; ++nt) {
                const int n = nt * 16 + n16;
                const f16x4 rx = *(const f16x4*)&xp[n][h * 64 + obase];
                float p = 0.f;
                #pragma unroll
                for (int r = 0; r < 4; ++r) {
                    float v = acc3[h][nt][r] + bqa[r] + (float)rx[r];
                    v = fmaxf(v, 0.f);
                    p += v * fcv[h][r];
                }
                part[nt] += p;
            }
        }
        #pragma unroll
        for (int off_i = 0; off_i < 5; ++off_i) {
            const int off = (int[]){1, 2, 4, 16, 32}[off_i];
            part[0] += __shfl_xor(part[0], off, 64);
            part[1] += __shfl_xor(part[1], off, 64);
            part[2] += __shfl_xor(part[2], off, 64);
            part[3] += __shfl_xor(part[3], off, 64);
        }
        if ((lane & 55) == 0) {          // lanes 0 and 8
            const int par = (lane >> 3) & 1;
            wsum[wv][0 + par] = part[0];
            wsum[wv][2 + par] = part[1];
            wsum[wv][4 + par] = part[2];
            wsum[wv][6 + par] = part[3];
        }
    }
    __syncthreads();   // B5

    if (tid < 8) {
        const float s = wsum[0][tid] + wsum[1][tid] + wsum[2][tid] + wsum[3][tid];
        out[img * 2048 + mblk * 8 + tid] = s + fc2b[0];
    }
}

// ---------------------------------------------------------------------------
extern "C" void kernel_launch(void* const* d_in, const int* in_sizes, int n_in,
                              void* d_out, int out_size, void* d_ws, size_t ws_size,
                              hipStream_t stream) {
    const float* feature = (const float*)d_in[0];
    const float* lines   = (const float*)d_in[1];
    const float* fc1_w   = (const float*)d_in[2];
    const float* fc1_b   = (const float*)d_in[3];
    const float* bn1g    = (const float*)d_in[4];
    const float* bn1b    = (const float*)d_in[5];
    const float* bn1m    = (const float*)d_in[6];
    const float* bn1v    = (const float*)d_in[7];
    const float* w1      = (const float*)d_in[8];
    const float* b1      = (const float*)d_in[9];
    const float* bn2g    = (const float*)d_in[10];
    const float* bn2b    = (const float*)d_in[11];
    const float* bn2m    = (const float*)d_in[12];
    const float* bn2v    = (const float*)d_in[13];
    const float* w2      = (const float*)d_in[14];
    const float* b2      = (const float*)d_in[15];
    const float* bn3g    = (const float*)d_in[16];
    const float* bn3b    = (const float*)d_in[17];
    const float* bn3m    = (const float*)d_in[18];
    const float* bn3v    = (const float*)d_in[19];
    const float* w3      = (const float*)d_in[20];
    const float* b3      = (const float*)d_in[21];
    const float* fc2w    = (const float*)d_in[22];
    const float* fc2b    = (const float*)d_in[23];

    f16* xmap = (f16*)d_ws;                                      // 32 MiB
    f16* wsp  = (f16*)((char*)d_ws + (size_t)32 * 1024 * 1024);  // 120 KiB

    wprep_kernel<<<240, 256, 0, stream>>>(fc1_w, w1, w2, w3, wsp);
    fc1_mfma<<<512, 1024, 0, stream>>>(feature, wsp, fc1_b, xmap);
    loi_kernel<<<2048, 256, 0, stream>>>(xmap, lines, wsp,
                                         bn1g, bn1b, bn1m, bn1v, b1,
                                         bn2g, bn2b, bn2m, bn2v, b2,
                                         bn3g, bn3b, bn3m, bn3v, b3,
                                         fc2w, fc2b, (float*)d_out);
}

// Round 8
// 277.291 us; speedup vs baseline: 1.0207x; 1.0031x over previous
//
#include <hip/hip_runtime.h>

#define EPSBN 1e-5f

typedef _Float16 f16;
typedef _Float16 f16x8 __attribute__((ext_vector_type(8)));
typedef _Float16 f16x4 __attribute__((ext_vector_type(4)));
typedef _Float16 f16x2 __attribute__((ext_vector_type(2)));
typedef float    f32x4 __attribute__((ext_vector_type(4)));

#define AS1 __attribute__((address_space(1)))
#define AS3 __attribute__((address_space(3)))

__device__ inline f16x8 hmax8(f16x8 a, f16x8 b) {
    f16x8 r;
    #pragma unroll
    for (int i = 0; i < 8; ++i) r[i] = a[i] > b[i] ? a[i] : b[i];
    return r;
}
__device__ inline f16x8 relu8(f16x8 v) {
    f16x8 r;
    #pragma unroll
    for (int i = 0; i < 8; ++i) r[i] = v[i] > (f16)0.f ? v[i] : (f16)0.f;
    return r;
}

// ---------------------------------------------------------------------------
// wprep: weights -> f16.
// region0 [0,32768): fc1 W, LANE-INTERLEAVED fragment order (conflict-free
// ds_read_b128: lane stride 16 B):
//   wfrag[s(8)][ow(2)][t(4)][lane(64)][k8(8)]
//   value = fc1w[o = ow*64 + t*16 + (lane&15)][k = s*32 + (lane>>4)*8 + k8]
// w1 [32768,40960) ; w2 as [tau][o][i] [40960,53248) ; w3 [53248,61440)
// ---------------------------------------------------------------------------
__global__ void wprep_kernel(const float* __restrict__ fc1w,
                             const float* __restrict__ w1,
                             const float* __restrict__ w2,
                             const float* __restrict__ w3,
                             f16* __restrict__ dst) {
    const int i = blockIdx.x * 256 + threadIdx.x;   // 61440 total
    float v;
    if (i < 32768) {
        const int k8   = i & 7;
        const int lane = (i >> 3) & 63;
        const int t    = (i >> 9) & 3;
        const int ow   = (i >> 11) & 1;
        const int s    = (i >> 12) & 7;
        const int n16l = lane & 15, quadl = lane >> 4;
        v = fc1w[(ow * 64 + t * 16 + n16l) * 256 + s * 32 + quadl * 8 + k8];
    }
    else if (i < 40960) v = w1[i - 32768];
    else if (i < 53248) {
        const int j = i - 40960, tau = j >> 12, rest = j & 4095;
        v = w2[rest * 3 + tau];
    } else              v = w3[i - 53248];
    dst[i] = (f16)v;
}

// ---------------------------------------------------------------------------
// fc1 v7: float4 staging (the untested shape axis).
// v2/v4/v5/v6 (66/62/63/58.6 us) varied staging mechanism, vmcnt discipline,
// LDS banking -- together <=8 us.  All used <=4 B/lane scalar loads in
// <=256 B runs.  The 6.3 TB/s ceiling (m13) is for float4 16 B/lane 1 KB/instr
// copies; scalar loads cost ~2x (G13).  v7:
//   - 512-pt tiles, grid 256 = 1 block/CU single pass; img=bid&7 XCD pin.
//   - staging thread = (pg: 4 pts, chg: 4 ch): 4x float4/stage, each wave-load
//     a contiguous 1 KB run; cvt in reg; 4x ds_write_b64 slot-swizzled
//     (chg>>1)^((pt>>2)&3) (read: quad^((pt>>2)&3) -- same involution).
//   - kept from v6: W-in-LDS lane-interleaved frags, reg-staged prefetch
//     (1-deep), lgkm-only barriers, epilogue via LDS.
// LDS: W 64 KB + xb[2][512][32] 64 KB (unions epi) = 128 KB, 16 waves/CU.
// ---------------------------------------------------------------------------
__global__ __launch_bounds__(1024, 4)
void fc1_mfma(const float* __restrict__ feat,   // [8][256][16384] f32
              const f16*   __restrict__ wfrag,  // [8][2][4][64][8] f16
              const float* __restrict__ bias,   // [128]
              f16*         __restrict__ xmap) { // [8][16384][128] f16
    __shared__ f16 wlds[32768];                  // 64 KB
    __shared__ union {
        f16 xb[2][512][32];                      // 65536 B (2 stage buffers)
        f16 epi[128][136];                       // 34816 B (epilogue staging)
    } u;

    const int tid  = threadIdx.x;
    const int wv   = tid >> 6;                   // 0..15
    const int lane = tid & 63;
    const int n16  = lane & 15, quad = lane >> 4;
    const int ow   = wv & 1;                     // o-half (64 outputs)
    const int tw0  = wv >> 1;                    // first pt-tile (0..7); second = +8
    const int img  = blockIdx.x & 7;             // XCD pin (same as loi)
    const int p0   = (blockIdx.x >> 3) << 9;     // 512-pt tile

    const float* fimg = feat + (((size_t)img) << 22);

    // staging map: thread -> (pg: pts pg*4..+3, chg: channels chg*4..+3)
    const int chg = tid >> 7;                    // 0..7 (wave-constant)
    const int pg  = tid & 127;                   // 0..127
    const float* sb = fimg + p0 + pg * 4;

    f32x4 acc[2][2][4];
    #pragma unroll
    for (int h = 0; h < 2; ++h)
        #pragma unroll
        for (int ptg = 0; ptg < 2; ++ptg)
            #pragma unroll
            for (int t = 0; t < 4; ++t) acc[h][ptg][t] = (f32x4){0.f, 0.f, 0.f, 0.f};

    float4 st4[4];
    auto load_stage = [&](int s) {
        #pragma unroll
        for (int cc = 0; cc < 4; ++cc)
            st4[cc] = *(const float4*)(sb + (((size_t)(s * 32 + chg * 4 + cc)) << 14));
    };
    auto write_stage = [&](int s) {
        #pragma unroll
        for (int pp = 0; pp < 4; ++pp) {
            const int pt   = pg * 4 + pp;
            const int slot = (chg >> 1) ^ ((pt >> 2) & 3);
            f16x4 h;
            h[0] = (f16)st4[0][pp]; h[1] = (f16)st4[1][pp];
            h[2] = (f16)st4[2][pp]; h[3] = (f16)st4[3][pp];
            *(f16x4*)&u.xb[s & 1][pt][slot * 8 + (chg & 1) * 4] = h;
        }
    };

    // ---- prologue: W DMA (4 linear 1 KB chunks/wave) + stage 0 ----
    #pragma unroll
    for (int c4 = 0; c4 < 4; ++c4) {
        const int c = wv + 16 * c4;
        __builtin_amdgcn_global_load_lds((const AS1 void*)(wfrag + c * 512 + lane * 8),
                                         (AS3 void*)(wlds + c * 512), 16, 0, 0);
    }
    load_stage(0);
    write_stage(0);                                    // auto-waits stage0 loads
    asm volatile("s_waitcnt vmcnt(0)" ::: "memory");   // W DMA landed (prologue only)
    __syncthreads();

    // ---- main loop: 8 K-stages ----
    #pragma unroll
    for (int s = 0; s < 8; ++s) {
        if (s < 7) load_stage(s + 1);                  // issue early (1-deep)

        // W fragments: lane-interleaved, conflict-free b128
        f16x8 wf[4];
        #pragma unroll
        for (int t = 0; t < 4; ++t)
            wf[t] = *(const f16x8*)&wlds[(((s * 2 + ow) * 4 + t) * 64 + lane) * 8];

        #pragma unroll
        for (int h = 0; h < 2; ++h) {
            const int tile = tw0 + h * 8;
            f16x8 xf[2];
            #pragma unroll
            for (int ptg = 0; ptg < 2; ++ptg) {
                const int pt = tile * 32 + ptg * 16 + n16;
                xf[ptg] = *(const f16x8*)&u.xb[s & 1][pt][(quad ^ ((pt >> 2) & 3)) << 3];
            }
            #pragma unroll
            for (int ptg = 0; ptg < 2; ++ptg)
                #pragma unroll
                for (int t = 0; t < 4; ++t)
                    acc[h][ptg][t] = __builtin_amdgcn_mfma_f32_16x16x32_f16(
                        wf[t], xf[ptg], acc[h][ptg][t], 0, 0, 0);
        }

        if (s < 7) {
            write_stage(s + 1);    // auto-wait counts only this stage's loads

            __builtin_amdgcn_sched_barrier(0);
            asm volatile("s_waitcnt lgkmcnt(0)" ::: "memory");  // ds only
            __builtin_amdgcn_sched_barrier(0);
            __builtin_amdgcn_s_barrier();
            __builtin_amdgcn_sched_barrier(0);
        }
    }

    // ---- epilogue: 4 passes of 128 rows through u.epi ----
    #pragma unroll
    for (int P = 0; P < 4; ++P) {
        __syncthreads();
        const int hh = (P >= 2);
        if ((wv >> 3) == (P & 1)) {
            #pragma unroll
            for (int ptg = 0; ptg < 2; ++ptg) {
                const int rowl = (tw0 & 3) * 32 + ptg * 16 + n16;
                #pragma unroll
                for (int t = 0; t < 4; ++t) {
                    const int o = ow * 64 + t * 16 + quad * 4;
                    const float4 bq = *(const float4*)&bias[o];
                    f16x4 hv;
                    hv[0] = (f16)(acc[hh][ptg][t][0] + bq.x);
                    hv[1] = (f16)(acc[hh][ptg][t][1] + bq.y);
                    hv[2] = (f16)(acc[hh][ptg][t][2] + bq.z);
                    hv[3] = (f16)(acc[hh][ptg][t][3] + bq.w);
                    *(f16x4*)&u.epi[rowl][o] = hv;
                }
            }
        }
        __syncthreads();
        #pragma unroll
        for (int it = 0; it < 2; ++it) {
            const int idx = it * 1024 + tid;
            const int rowl = idx >> 4, seg = idx & 15;
            const float4 v = *(const float4*)&u.epi[rowl][seg * 8];
            *(float4*)&xmap[(((size_t)(img * 16384 + p0 + P * 128 + rowl)) << 7) + seg * 8] = v;
        }
    }
}

// ---------------------------------------------------------------------------
// loi: unchanged (63.5 us).  8 lines/block, XCD-pinned gathers, 16-B gathers
// (8 ch/lane), pool samples split across lane-halves + shfl_xor(16) max,
// conv1/conv2/conv3 MFMA, residual+relu+fc2.
// ---------------------------------------------------------------------------
__global__ __launch_bounds__(256)
void loi_kernel(const f16*   __restrict__ x,       // [8][16384][128] f16
                const float* __restrict__ lines,
                const f16*   __restrict__ wsp,
                const float* __restrict__ bn1g, const float* __restrict__ bn1b,
                const float* __restrict__ bn1m, const float* __restrict__ bn1v,
                const float* __restrict__ b1,
                const float* __restrict__ bn2g, const float* __restrict__ bn2b,
                const float* __restrict__ bn2m, const float* __restrict__ bn2v,
                const float* __restrict__ b2,
                const float* __restrict__ bn3g, const float* __restrict__ bn3b,
                const float* __restrict__ bn3m, const float* __restrict__ bn3v,
                const float* __restrict__ b3,
                const float* __restrict__ fc2w, const float* __restrict__ fc2b,
                float* __restrict__ out) {
    __shared__ f16 xp[64][136];                       // 17408 B
    __shared__ alignas(16) union {
        struct { int toff[256][4]; f16 twgt[256][4]; } tp;     // 6144 B
        struct { f16 h1[80][72]; f16 h2[64][72]; } cv;         // 20736 B
    } u;
    __shared__ f16 s1h[128], t1h[128];                // 512 B
    __shared__ float s2f[64], t2f[64], s3f[64], t3f[64], b1f[64], b2f[64];
    __shared__ float b3f[128];
    __shared__ float wsum[4][8];

    const f16* w1f16 = wsp + 32768;
    const f16* w2f16 = wsp + 40960;
    const f16* w3f16 = wsp + 53248;

    const int tid  = threadIdx.x;
    const int wv   = tid >> 6, lane = tid & 63;
    const int n16  = lane & 15, quad = lane >> 4;
    const int img  = blockIdx.x & 7;                  // XCD swizzle
    const int mblk = blockIdx.x >> 3;                 // 0..255 within image

    // ---- LUTs ----
    if (tid < 128) {
        const float s = bn1g[tid] * rsqrtf(bn1v[tid] + EPSBN);
        s1h[tid] = (f16)s; t1h[tid] = (f16)(bn1b[tid] - bn1m[tid] * s);
    }
    if (tid < 64) {
        const float s = bn2g[tid] * rsqrtf(bn2v[tid] + EPSBN);
        s2f[tid] = s; t2f[tid] = bn2b[tid] - bn2m[tid] * s;
        b1f[tid] = b1[tid];
    } else if (tid < 128) {
        const int c = tid - 64;
        const float s = bn3g[c] * rsqrtf(bn3v[c] + EPSBN);
        s3f[c] = s; t3f[c] = bn3b[c] - bn3m[c] * s;
        b2f[c] = b2[c];
    } else {
        b3f[tid - 128] = b3[tid - 128];
    }

    // ---- interp tuples: one per (line, pt) ----
    {
        const int li = tid >> 5, pt = tid & 31;
        const int gl = img * 2048 + mblk * 8 + li;
        const float4 ln = *(const float4*)&lines[gl * 4];
        const float lam = (float)pt * (1.0f / 31.0f);
        const float px = ln.x * lam + ln.z * (1.f - lam) - 0.5f;
        const float py = ln.y * lam + ln.w * (1.f - lam) - 0.5f;
        const float px0 = fminf(fmaxf(floorf(px), 0.f), 127.f);
        const float py0 = fminf(fmaxf(floorf(py), 0.f), 127.f);
        const float px1 = fminf(px0 + 1.f, 127.f);
        const float py1 = fminf(py0 + 1.f, 127.f);
        const int ix0 = (int)px0, iy0 = (int)py0;
        const int ix1 = (int)px1, iy1 = (int)py1;
        u.tp.toff[tid][0] = (((ix0 << 7) + iy0) << 7);
        u.tp.toff[tid][1] = (((ix1 << 7) + iy0) << 7);
        u.tp.toff[tid][2] = (((ix0 << 7) + iy1) << 7);
        u.tp.toff[tid][3] = (((ix1 << 7) + iy1) << 7);
        const float wx1 = px1 - px, wx0 = px - px0;
        const float wy1 = py1 - py, wy0 = py - py0;
        u.tp.twgt[tid][0] = (f16)(wx1 * wy1); u.tp.twgt[tid][1] = (f16)(wx0 * wy1);
        u.tp.twgt[tid][2] = (f16)(wx1 * wy0); u.tp.twgt[tid][3] = (f16)(wx0 * wy0);
    }
    __syncthreads();   // B1

    // ---- sampling + maxpool: 8 ch/lane (16 B gathers), 2 samples/lane-half,
    //      shfl_xor(16) final max ----
    {
        const int h  = lane >> 5;            // line parity within wave
        const int sh = (lane >> 4) & 1;      // which half of the 4 pool samples
        const int j  = lane & 15;            // 8-channel group
        const int li = wv * 2 + h;
        const f16* xbh = x + (((size_t)img) << 21) + 8 * j;
        #pragma unroll
        for (int t = 0; t < 8; ++t) {
            f16x8 m;
            #pragma unroll
            for (int q = 0; q < 8; ++q) m[q] = (f16)(-60000.f);
            #pragma unroll
            for (int ss = 0; ss < 2; ++ss) {
                const int combo = li * 32 + t * 4 + sh * 2 + ss;
                const int4  off = *(const int4*)&u.tp.toff[combo][0];
                const f16x4 tw  = *(const f16x4*)&u.tp.twgt[combo][0];
                const f16x8 g00 = *(const f16x8*)(xbh + off.x);
                const f16x8 g10 = *(const f16x8*)(xbh + off.y);
                const f16x8 g01 = *(const f16x8*)(xbh + off.z);
                const f16x8 g11 = *(const f16x8*)(xbh + off.w);
                f16x8 w0, w1v, w2v, w3v;
                #pragma unroll
                for (int q = 0; q < 8; ++q) {
                    w0[q] = tw[0]; w1v[q] = tw[1]; w2v[q] = tw[2]; w3v[q] = tw[3];
                }
                const f16x8 v = g00 * w0 + g10 * w1v + g01 * w2v + g11 * w3v;
                m = hmax8(m, v);
            }
            union { f16x8 v8; int i4[4]; } cv;
            cv.v8 = m;
            #pragma unroll
            for (int q = 0; q < 4; ++q) cv.i4[q] = __shfl_xor(cv.i4[q], 16, 64);
            m = hmax8(m, cv.v8);
            if (sh == 0) *(f16x8*)&xp[li * 8 + t][8 * j] = m;
        }
    }
    __syncthreads();   // B2 (tuples dead; xp ready)

    // ---- zero h1 guard rows ----
    {
        const int r = tid >> 4, seg = tid & 15;
        const int row = (r >> 1) * 10 + (r & 1) * 9;
        *(unsigned long long*)&u.cv.h1[row][seg * 4] = 0ull;
    }

    // ---- conv1 + fused bn1/relu (packed f16) ----
    {
        const int o_lane = wv * 16 + n16;
        f32x4 acc1[4];
        #pragma unroll
        for (int nt = 0; nt < 4; ++nt) acc1[nt] = (f32x4){0.f, 0.f, 0.f, 0.f};
        #pragma unroll
        for (int ks = 0; ks < 4; ++ks) {
            const int k = ks * 32 + quad * 8;
            const f16x8 a  = *(const f16x8*)&w1f16[o_lane * 128 + k];
            const f16x8 s8 = *(const f16x8*)&s1h[k];
            const f16x8 t8 = *(const f16x8*)&t1h[k];
            #pragma unroll
            for (int nt = 0; nt < 4; ++nt) {
                const f16x8 raw = *(const f16x8*)&xp[nt * 16 + n16][k];
                const f16x8 bf = relu8(raw * s8 + t8);
                acc1[nt] = __builtin_amdgcn_mfma_f32_16x16x32_f16(a, bf, acc1[nt], 0, 0, 0);
            }
        }
        #pragma unroll
        for (int nt = 0; nt < 4; ++nt) {
            const int n = nt * 16 + n16;
            const int nprow = (n >> 3) * 10 + (n & 7) + 1;
            #pragma unroll
            for (int r = 0; r < 4; ++r) {
                const int o = wv * 16 + quad * 4 + r;
                const float v = fmaxf((acc1[nt][r] + b1f[o]) * s2f[o] + t2f[o], 0.f);
                u.cv.h1[nprow][o] = (f16)v;
            }
        }
    }
    __syncthreads();   // B3

    // ---- conv2: 3 shifted [64x64] matmuls ----
    {
        const int o_lane = wv * 16 + n16;
        f32x4 acc2[4];
        #pragma unroll
        for (int nt = 0; nt < 4; ++nt) acc2[nt] = (f32x4){0.f, 0.f, 0.f, 0.f};
        #pragma unroll
        for (int d = 0; d < 3; ++d) {
            const f16* A2 = w2f16 + d * 4096;
            #pragma unroll
            for (int ks = 0; ks < 2; ++ks) {
                const int k = ks * 32 + quad * 8;
                const f16x8 a = *(const f16x8*)&A2[o_lane * 64 + k];
                #pragma unroll
                for (int nt = 0; nt < 4; ++nt) {
                    const int n = nt * 16 + n16;
                    const int row = (n >> 3) * 10 + (n & 7) + d;
                    const f16x8 bf = *(const f16x8*)&u.cv.h1[row][k];
                    acc2[nt] = __builtin_amdgcn_mfma_f32_16x16x32_f16(a, bf, acc2[nt], 0, 0, 0);
                }
            }
        }
        #pragma unroll
        for (int nt = 0; nt < 4; ++nt) {
            const int n = nt * 16 + n16;
            #pragma unroll
            for (int r = 0; r < 4; ++r) {
                const int o = wv * 16 + quad * 4 + r;
                const float v = fmaxf((acc2[nt][r] + b2f[o]) * s3f[o] + t3f[o], 0.f);
                u.cv.h2[n][o] = (f16)v;
            }
        }
    }
    __syncthreads();   // B4

    // ---- conv3 + residual + relu + fc2 ----
    {
        const int col = n16 & 7, obase = wv * 16 + quad * 4;
        float fcv[2][4];
        #pragma unroll
        for (int h = 0; h < 2; ++h)
            #pragma unroll
            for (int r = 0; r < 4; ++r)
                fcv[h][r] = fc2w[(h * 64 + obase + r) * 8 + col];

        f32x4 acc3[2][4];
        #pragma unroll
        for (int h = 0; h < 2; ++h)
            #pragma unroll
            for (int nt = 0; nt < 4; ++nt) acc3[h][nt] = (f32x4){0.f, 0.f, 0.f, 0.f};
        #pragma unroll
        for (int ks = 0; ks < 2; ++ks) {
            const int k = ks * 32 + quad * 8;
            const f16x8 a0 = *(const f16x8*)&w3f16[(wv * 16 + n16) * 64 + k];
            const f16x8 a1 = *(const f16x8*)&w3f16[(64 + wv * 16 + n16) * 64 + k];
            #pragma unroll
            for (int nt = 0; nt < 4; ++nt) {
                const f16x8 bf = *(const f16x8*)&u.cv.h2[nt * 16 + n16][k];
                acc3[0][nt] = __builtin_amdgcn_mfma_f32_16x16x32_f16(a0, bf, acc3[0][nt], 0, 0, 0);
                acc3[1][nt] = __builtin_amdgcn_mfma_f32_16x16x32_f16(a1, bf, acc3[1][nt], 0, 0, 0);
            }
        }
        float part[4] = {0.f, 0.f, 0.f, 0.f};
        #pragma unroll
        for (int h = 0; h < 2; ++h) {
            const float4 bq = *(const float4*)&b3f[h * 64 + obase];
            const float bqa[4] = {bq.x, bq.y, bq.z, bq.w};
            #pragma unroll
            for (int nt = 0; nt < 4; ++nt) {
                const int n = nt * 16 + n16;
                const f16x4 rx = *(const f16x4*)&xp[n][h * 64 + obase];
                float p = 0.f;
                #pragma unroll
                for (int r = 0; r < 4; ++r) {
                    float v = acc3[h][nt][r] + bqa[r] + (float)rx[r];
                    v = fmaxf(v, 0.f);
                    p += v * fcv[h][r];
                }
                part[nt] += p;
            }
        }
        #pragma unroll
        for (int off_i = 0; off_i < 5; ++off_i) {
            const int off = (int[]){1, 2, 4, 16, 32}[off_i];
            part[0] += __shfl_xor(part[0], off, 64);
            part[1] += __shfl_xor(part[1], off, 64);
            part[2] += __shfl_xor(part[2], off, 64);
            part[3] += __shfl_xor(part[3], off, 64);
        }
        if ((lane & 55) == 0) {          // lanes 0 and 8
            const int par = (lane >> 3) & 1;
            wsum[wv][0 + par] = part[0];
            wsum[wv][2 + par] = part[1];
            wsum[wv][4 + par] = part[2];
            wsum[wv][6 + par] = part[3];
        }
    }
    __syncthreads();   // B5

    if (tid < 8) {
        const float s = wsum[0][tid] + wsum[1][tid] + wsum[2][tid] + wsum[3][tid];
        out[img * 2048 + mblk * 8 + tid] = s + fc2b[0];
    }
}

// ---------------------------------------------------------------------------
extern "C" void kernel_launch(void* const* d_in, const int* in_sizes, int n_in,
                              void* d_out, int out_size, void* d_ws, size_t ws_size,
                              hipStream_t stream) {
    const float* feature = (const float*)d_in[0];
    const float* lines   = (const float*)d_in[1];
    const float* fc1_w   = (const float*)d_in[2];
    const float* fc1_b   = (const float*)d_in[3];
    const float* bn1g    = (const float*)d_in[4];
    const float* bn1b    = (const float*)d_in[5];
    const float* bn1m    = (const float*)d_in[6];
    const float* bn1v    = (const float*)d_in[7];
    const float* w1      = (const float*)d_in[8];
    const float* b1      = (const float*)d_in[9];
    const float* bn2g    = (const float*)d_in[10];
    const float* bn2b    = (const float*)d_in[11];
    const float* bn2m    = (const float*)d_in[12];
    const float* bn2v    = (const float*)d_in[13];
    const float* w2      = (const float*)d_in[14];
    const float* b2      = (const float*)d_in[15];
    const float* bn3g    = (const float*)d_in[16];
    const float* bn3b    = (const float*)d_in[17];
    const float* bn3m    = (const float*)d_in[18];
    const float* bn3v    = (const float*)d_in[19];
    const float* w3      = (const float*)d_in[20];
    const float* b3      = (const float*)d_in[21];
    const float* fc2w    = (const float*)d_in[22];
    const float* fc2b    = (const float*)d_in[23];

    f16* xmap = (f16*)d_ws;                                      // 32 MiB
    f16* wsp  = (f16*)((char*)d_ws + (size_t)32 * 1024 * 1024);  // 120 KiB

    wprep_kernel<<<240, 256, 0, stream>>>(fc1_w, w1, w2, w3, wsp);
    fc1_mfma<<<256, 1024, 0, stream>>>(feature, wsp, fc1_b, xmap);
    loi_kernel<<<2048, 256, 0, stream>>>(xmap, lines, wsp,
                                         bn1g, bn1b, bn1m, bn1v, b1,
                                         bn2g, bn2b, bn2m, bn2v, b2,
                                         bn3g, bn3b, bn3m, bn3v, b3,
                                         fc2w, fc2b, (float*)d_out);
}

// Round 9
// 274.326 us; speedup vs baseline: 1.0317x; 1.0108x over previous
//
#include <hip/hip_runtime.h>

#define EPSBN 1e-5f

typedef _Float16 f16;
typedef _Float16 f16x8 __attribute__((ext_vector_type(8)));
typedef _Float16 f16x4 __attribute__((ext_vector_type(4)));
typedef _Float16 f16x2 __attribute__((ext_vector_type(2)));
typedef float    f32x4 __attribute__((ext_vector_type(4)));

#define AS1 __attribute__((address_space(1)))
#define AS3 __attribute__((address_space(3)))

__device__ inline f16x8 hmax8(f16x8 a, f16x8 b) {
    f16x8 r;
    #pragma unroll
    for (int i = 0; i < 8; ++i) r[i] = a[i] > b[i] ? a[i] : b[i];
    return r;
}
__device__ inline f16x8 relu8(f16x8 v) {
    f16x8 r;
    #pragma unroll
    for (int i = 0; i < 8; ++i) r[i] = v[i] > (f16)0.f ? v[i] : (f16)0.f;
    return r;
}

// ---------------------------------------------------------------------------
// wprep: weights -> f16.
// region0 [0,32768): fc1 W, LANE-INTERLEAVED fragment order (conflict-free
// ds_read_b128: lane stride 16 B):
//   wfrag[s(8)][ow(2)][t(4)][lane(64)][k8(8)]
//   value = fc1w[o = ow*64 + t*16 + (lane&15)][k = s*32 + (lane>>4)*8 + k8]
// w1 [32768,40960) ; w2 as [tau][o][i] [40960,53248) ; w3 [53248,61440)
// ---------------------------------------------------------------------------
__global__ void wprep_kernel(const float* __restrict__ fc1w,
                             const float* __restrict__ w1,
                             const float* __restrict__ w2,
                             const float* __restrict__ w3,
                             f16* __restrict__ dst) {
    const int i = blockIdx.x * 256 + threadIdx.x;   // 61440 total
    float v;
    if (i < 32768) {
        const int k8   = i & 7;
        const int lane = (i >> 3) & 63;
        const int t    = (i >> 9) & 3;
        const int ow   = (i >> 11) & 1;
        const int s    = (i >> 12) & 7;
        const int n16l = lane & 15, quadl = lane >> 4;
        v = fc1w[(ow * 64 + t * 16 + n16l) * 256 + s * 32 + quadl * 8 + k8];
    }
    else if (i < 40960) v = w1[i - 32768];
    else if (i < 53248) {
        const int j = i - 40960, tau = j >> 12, rest = j & 4095;
        v = w2[rest * 3 + tau];
    } else              v = w3[i - 53248];
    dst[i] = (f16)v;
}

// ---------------------------------------------------------------------------
// fc1 v8: UNPINNED from XCDs (the round-8 A/B variable).
// Five fc1 structures (66/62/63/58.6/57.8 us) varied staging, vmcnt, LDS
// banking, load shape -- combined <=8 us; per-CU delivery stuck at ~9-11 GB/s
// vs 24 GB/s/CU copy ceiling.  The never-varied inherited variable:
// img = bid&7 routed ALL of image i's streaming 16.75 MB feature read
// through XCD i alone.  v8: img = bid>>5, tile = bid&31 -> each image's
// blocks spread round-robin over all 8 XCDs, streaming read at chip-wide BW.
// (Inter-kernel xmap-in-L2 was illusory anyway: same-stream visibility
// forces L2 writeback between dispatches; loi's INTRA-dispatch pin is kept.)
// Internals unchanged from v7: float4 staging, W-in-LDS lane-interleaved
// frags, reg-staged prefetch, lgkm-only barriers, epilogue via LDS.
// ---------------------------------------------------------------------------
__global__ __launch_bounds__(1024, 4)
void fc1_mfma(const float* __restrict__ feat,   // [8][256][16384] f32
              const f16*   __restrict__ wfrag,  // [8][2][4][64][8] f16
              const float* __restrict__ bias,   // [128]
              f16*         __restrict__ xmap) { // [8][16384][128] f16
    __shared__ f16 wlds[32768];                  // 64 KB
    __shared__ union {
        f16 xb[2][512][32];                      // 65536 B (2 stage buffers)
        f16 epi[128][136];                       // 34816 B (epilogue staging)
    } u;

    const int tid  = threadIdx.x;
    const int wv   = tid >> 6;                   // 0..15
    const int lane = tid & 63;
    const int n16  = lane & 15, quad = lane >> 4;
    const int ow   = wv & 1;                     // o-half (64 outputs)
    const int tw0  = wv >> 1;                    // first pt-tile (0..7); second = +8
    const int img  = blockIdx.x >> 5;            // UNPINNED: image grouped,
    const int p0   = (blockIdx.x & 31) << 9;     // tiles round-robin over XCDs

    const float* fimg = feat + (((size_t)img) << 22);

    // staging map: thread -> (pg: pts pg*4..+3, chg: channels chg*4..+3)
    const int chg = tid >> 7;                    // 0..7 (wave-constant)
    const int pg  = tid & 127;                   // 0..127
    const float* sb = fimg + p0 + pg * 4;

    f32x4 acc[2][2][4];
    #pragma unroll
    for (int h = 0; h < 2; ++h)
        #pragma unroll
        for (int ptg = 0; ptg < 2; ++ptg)
            #pragma unroll
            for (int t = 0; t < 4; ++t) acc[h][ptg][t] = (f32x4){0.f, 0.f, 0.f, 0.f};

    float4 st4[4];
    auto load_stage = [&](int s) {
        #pragma unroll
        for (int cc = 0; cc < 4; ++cc)
            st4[cc] = *(const float4*)(sb + (((size_t)(s * 32 + chg * 4 + cc)) << 14));
    };
    auto write_stage = [&](int s) {
        #pragma unroll
        for (int pp = 0; pp < 4; ++pp) {
            const int pt   = pg * 4 + pp;
            const int slot = (chg >> 1) ^ ((pt >> 2) & 3);
            f16x4 h;
            h[0] = (f16)st4[0][pp]; h[1] = (f16)st4[1][pp];
            h[2] = (f16)st4[2][pp]; h[3] = (f16)st4[3][pp];
            *(f16x4*)&u.xb[s & 1][pt][slot * 8 + (chg & 1) * 4] = h;
        }
    };

    // ---- prologue: W DMA (4 linear 1 KB chunks/wave) + stage 0 ----
    #pragma unroll
    for (int c4 = 0; c4 < 4; ++c4) {
        const int c = wv + 16 * c4;
        __builtin_amdgcn_global_load_lds((const AS1 void*)(wfrag + c * 512 + lane * 8),
                                         (AS3 void*)(wlds + c * 512), 16, 0, 0);
    }
    load_stage(0);
    write_stage(0);                                    // auto-waits stage0 loads
    asm volatile("s_waitcnt vmcnt(0)" ::: "memory");   // W DMA landed (prologue only)
    __syncthreads();

    // ---- main loop: 8 K-stages ----
    #pragma unroll
    for (int s = 0; s < 8; ++s) {
        if (s < 7) load_stage(s + 1);                  // issue early (1-deep)

        // W fragments: lane-interleaved, conflict-free b128
        f16x8 wf[4];
        #pragma unroll
        for (int t = 0; t < 4; ++t)
            wf[t] = *(const f16x8*)&wlds[(((s * 2 + ow) * 4 + t) * 64 + lane) * 8];

        #pragma unroll
        for (int h = 0; h < 2; ++h) {
            const int tile = tw0 + h * 8;
            f16x8 xf[2];
            #pragma unroll
            for (int ptg = 0; ptg < 2; ++ptg) {
                const int pt = tile * 32 + ptg * 16 + n16;
                xf[ptg] = *(const f16x8*)&u.xb[s & 1][pt][(quad ^ ((pt >> 2) & 3)) << 3];
            }
            #pragma unroll
            for (int ptg = 0; ptg < 2; ++ptg)
                #pragma unroll
                for (int t = 0; t < 4; ++t)
                    acc[h][ptg][t] = __builtin_amdgcn_mfma_f32_16x16x32_f16(
                        wf[t], xf[ptg], acc[h][ptg][t], 0, 0, 0);
        }

        if (s < 7) {
            write_stage(s + 1);    // auto-wait counts only this stage's loads

            __builtin_amdgcn_sched_barrier(0);
            asm volatile("s_waitcnt lgkmcnt(0)" ::: "memory");  // ds only
            __builtin_amdgcn_sched_barrier(0);
            __builtin_amdgcn_s_barrier();
            __builtin_amdgcn_sched_barrier(0);
        }
    }

    // ---- epilogue: 4 passes of 128 rows through u.epi ----
    #pragma unroll
    for (int P = 0; P < 4; ++P) {
        __syncthreads();
        const int hh = (P >= 2);
        if ((wv >> 3) == (P & 1)) {
            #pragma unroll
            for (int ptg = 0; ptg < 2; ++ptg) {
                const int rowl = (tw0 & 3) * 32 + ptg * 16 + n16;
                #pragma unroll
                for (int t = 0; t < 4; ++t) {
                    const int o = ow * 64 + t * 16 + quad * 4;
                    const float4 bq = *(const float4*)&bias[o];
                    f16x4 hv;
                    hv[0] = (f16)(acc[hh][ptg][t][0] + bq.x);
                    hv[1] = (f16)(acc[hh][ptg][t][1] + bq.y);
                    hv[2] = (f16)(acc[hh][ptg][t][2] + bq.z);
                    hv[3] = (f16)(acc[hh][ptg][t][3] + bq.w);
                    *(f16x4*)&u.epi[rowl][o] = hv;
                }
            }
        }
        __syncthreads();
        #pragma unroll
        for (int it = 0; it < 2; ++it) {
            const int idx = it * 1024 + tid;
            const int rowl = idx >> 4, seg = idx & 15;
            const float4 v = *(const float4*)&u.epi[rowl][seg * 8];
            *(float4*)&xmap[(((size_t)(img * 16384 + p0 + P * 128 + rowl)) << 7) + seg * 8] = v;
        }
    }
}

// ---------------------------------------------------------------------------
// loi: unchanged (63.5 us).  8 lines/block, XCD-pinned (KEPT: intra-dispatch
// reuse -- 256 blocks/img share a 4 MB xmap slice that fits XCD L2).
// 16-B gathers (8 ch/lane), pool samples split across lane-halves +
// shfl_xor(16) max, conv1/conv2/conv3 MFMA, residual+relu+fc2.
// ---------------------------------------------------------------------------
__global__ __launch_bounds__(256)
void loi_kernel(const f16*   __restrict__ x,       // [8][16384][128] f16
                const float* __restrict__ lines,
                const f16*   __restrict__ wsp,
                const float* __restrict__ bn1g, const float* __restrict__ bn1b,
                const float* __restrict__ bn1m, const float* __restrict__ bn1v,
                const float* __restrict__ b1,
                const float* __restrict__ bn2g, const float* __restrict__ bn2b,
                const float* __restrict__ bn2m, const float* __restrict__ bn2v,
                const float* __restrict__ b2,
                const float* __restrict__ bn3g, const float* __restrict__ bn3b,
                const float* __restrict__ bn3m, const float* __restrict__ bn3v,
                const float* __restrict__ b3,
                const float* __restrict__ fc2w, const float* __restrict__ fc2b,
                float* __restrict__ out) {
    __shared__ f16 xp[64][136];                       // 17408 B
    __shared__ alignas(16) union {
        struct { int toff[256][4]; f16 twgt[256][4]; } tp;     // 6144 B
        struct { f16 h1[80][72]; f16 h2[64][72]; } cv;         // 20736 B
    } u;
    __shared__ f16 s1h[128], t1h[128];                // 512 B
    __shared__ float s2f[64], t2f[64], s3f[64], t3f[64], b1f[64], b2f[64];
    __shared__ float b3f[128];
    __shared__ float wsum[4][8];

    const f16* w1f16 = wsp + 32768;
    const f16* w2f16 = wsp + 40960;
    const f16* w3f16 = wsp + 53248;

    const int tid  = threadIdx.x;
    const int wv   = tid >> 6, lane = tid & 63;
    const int n16  = lane & 15, quad = lane >> 4;
    const int img  = blockIdx.x & 7;                  // XCD swizzle
    const int mblk = blockIdx.x >> 3;                 // 0..255 within image

    // ---- LUTs ----
    if (tid < 128) {
        const float s = bn1g[tid] * rsqrtf(bn1v[tid] + EPSBN);
        s1h[tid] = (f16)s; t1h[tid] = (f16)(bn1b[tid] - bn1m[tid] * s);
    }
    if (tid < 64) {
        const float s = bn2g[tid] * rsqrtf(bn2v[tid] + EPSBN);
        s2f[tid] = s; t2f[tid] = bn2b[tid] - bn2m[tid] * s;
        b1f[tid] = b1[tid];
    } else if (tid < 128) {
        const int c = tid - 64;
        const float s = bn3g[c] * rsqrtf(bn3v[c] + EPSBN);
        s3f[c] = s; t3f[c] = bn3b[c] - bn3m[c] * s;
        b2f[c] = b2[c];
    } else {
        b3f[tid - 128] = b3[tid - 128];
    }

    // ---- interp tuples: one per (line, pt) ----
    {
        const int li = tid >> 5, pt = tid & 31;
        const int gl = img * 2048 + mblk * 8 + li;
        const float4 ln = *(const float4*)&lines[gl * 4];
        const float lam = (float)pt * (1.0f / 31.0f);
        const float px = ln.x * lam + ln.z * (1.f - lam) - 0.5f;
        const float py = ln.y * lam + ln.w * (1.f - lam) - 0.5f;
        const float px0 = fminf(fmaxf(floorf(px), 0.f), 127.f);
        const float py0 = fminf(fmaxf(floorf(py), 0.f), 127.f);
        const float px1 = fminf(px0 + 1.f, 127.f);
        const float py1 = fminf(py0 + 1.f, 127.f);
        const int ix0 = (int)px0, iy0 = (int)py0;
        const int ix1 = (int)px1, iy1 = (int)py1;
        u.tp.toff[tid][0] = (((ix0 << 7) + iy0) << 7);
        u.tp.toff[tid][1] = (((ix1 << 7) + iy0) << 7);
        u.tp.toff[tid][2] = (((ix0 << 7) + iy1) << 7);
        u.tp.toff[tid][3] = (((ix1 << 7) + iy1) << 7);
        const float wx1 = px1 - px, wx0 = px - px0;
        const float wy1 = py1 - py, wy0 = py - py0;
        u.tp.twgt[tid][0] = (f16)(wx1 * wy1); u.tp.twgt[tid][1] = (f16)(wx0 * wy1);
        u.tp.twgt[tid][2] = (f16)(wx1 * wy0); u.tp.twgt[tid][3] = (f16)(wx0 * wy0);
    }
    __syncthreads();   // B1

    // ---- sampling + maxpool: 8 ch/lane (16 B gathers), 2 samples/lane-half,
    //      shfl_xor(16) final max ----
    {
        const int h  = lane >> 5;            // line parity within wave
        const int sh = (lane >> 4) & 1;      // which half of the 4 pool samples
        const int j  = lane & 15;            // 8-channel group
        const int li = wv * 2 + h;
        const f16* xbh = x + (((size_t)img) << 21) + 8 * j;
        #pragma unroll
        for (int t = 0; t < 8; ++t) {
            f16x8 m;
            #pragma unroll
            for (int q = 0; q < 8; ++q) m[q] = (f16)(-60000.f);
            #pragma unroll
            for (int ss = 0; ss < 2; ++ss) {
                const int combo = li * 32 + t * 4 + sh * 2 + ss;
                const int4  off = *(const int4*)&u.tp.toff[combo][0];
                const f16x4 tw  = *(const f16x4*)&u.tp.twgt[combo][0];
                const f16x8 g00 = *(const f16x8*)(xbh + off.x);
                const f16x8 g10 = *(const f16x8*)(xbh + off.y);
                const f16x8 g01 = *(const f16x8*)(xbh + off.z);
                const f16x8 g11 = *(const f16x8*)(xbh + off.w);
                f16x8 w0, w1v, w2v, w3v;
                #pragma unroll
                for (int q = 0; q < 8; ++q) {
                    w0[q] = tw[0]; w1v[q] = tw[1]; w2v[q] = tw[2]; w3v[q] = tw[3];
                }
                const f16x8 v = g00 * w0 + g10 * w1v + g01 * w2v + g11 * w3v;
                m = hmax8(m, v);
            }
            union { f16x8 v8; int i4[4]; } cv;
            cv.v8 = m;
            #pragma unroll
            for (int q = 0; q < 4; ++q) cv.i4[q] = __shfl_xor(cv.i4[q], 16, 64);
            m = hmax8(m, cv.v8);
            if (sh == 0) *(f16x8*)&xp[li * 8 + t][8 * j] = m;
        }
    }
    __syncthreads();   // B2 (tuples dead; xp ready)

    // ---- zero h1 guard rows ----
    {
        const int r = tid >> 4, seg = tid & 15;
        const int row = (r >> 1) * 10 + (r & 1) * 9;
        *(unsigned long long*)&u.cv.h1[row][seg * 4] = 0ull;
    }

    // ---- conv1 + fused bn1/relu (packed f16) ----
    {
        const int o_lane = wv * 16 + n16;
        f32x4 acc1[4];
        #pragma unroll
        for (int nt = 0; nt < 4; ++nt) acc1[nt] = (f32x4){0.f, 0.f, 0.f, 0.f};
        #pragma unroll
        for (int ks = 0; ks < 4; ++ks) {
            const int k = ks * 32 + quad * 8;
            const f16x8 a  = *(const f16x8*)&w1f16[o_lane * 128 + k];
            const f16x8 s8 = *(const f16x8*)&s1h[k];
            const f16x8 t8 = *(const f16x8*)&t1h[k];
            #pragma unroll
            for (int nt = 0; nt < 4; ++nt) {
                const f16x8 raw = *(const f16x8*)&xp[nt * 16 + n16][k];
                const f16x8 bf = relu8(raw * s8 + t8);
                acc1[nt] = __builtin_amdgcn_mfma_f32_16x16x32_f16(a, bf, acc1[nt], 0, 0, 0);
            }
        }
        #pragma unroll
        for (int nt = 0; nt < 4; ++nt) {
            const int n = nt * 16 + n16;
            const int nprow = (n >> 3) * 10 + (n & 7) + 1;
            #pragma unroll
            for (int r = 0; r < 4; ++r) {
                const int o = wv * 16 + quad * 4 + r;
                const float v = fmaxf((acc1[nt][r] + b1f[o]) * s2f[o] + t2f[o], 0.f);
                u.cv.h1[nprow][o] = (f16)v;
            }
        }
    }
    __syncthreads();   // B3

    // ---- conv2: 3 shifted [64x64] matmuls ----
    {
        const int o_lane = wv * 16 + n16;
        f32x4 acc2[4];
        #pragma unroll
        for (int nt = 0; nt < 4; ++nt) acc2[nt] = (f32x4){0.f, 0.f, 0.f, 0.f};
        #pragma unroll
        for (int d = 0; d < 3; ++d) {
            const f16* A2 = w2f16 + d * 4096;
            #pragma unroll
            for (int ks = 0; ks < 2; ++ks) {
                const int k = ks * 32 + quad * 8;
                const f16x8 a = *(const f16x8*)&A2[o_lane * 64 + k];
                #pragma unroll
                for (int nt = 0; nt < 4; ++nt) {
                    const int n = nt * 16 + n16;
                    const int row = (n >> 3) * 10 + (n & 7) + d;
                    const f16x8 bf = *(const f16x8*)&u.cv.h1[row][k];
                    acc2[nt] = __builtin_amdgcn_mfma_f32_16x16x32_f16(a, bf, acc2[nt], 0, 0, 0);
                }
            }
        }
        #pragma unroll
        for (int nt = 0; nt < 4; ++nt) {
            const int n = nt * 16 + n16;
            #pragma unroll
            for (int r = 0; r < 4; ++r) {
                const int o = wv * 16 + quad * 4 + r;
                const float v = fmaxf((acc2[nt][r] + b2f[o]) * s3f[o] + t3f[o], 0.f);
                u.cv.h2[n][o] = (f16)v;
            }
        }
    }
    __syncthreads();   // B4

    // ---- conv3 + residual + relu + fc2 ----
    {
        const int col = n16 & 7, obase = wv * 16 + quad * 4;
        float fcv[2][4];
        #pragma unroll
        for (int h = 0; h < 2; ++h)
            #pragma unroll
            for (int r = 0; r < 4; ++r)
                fcv[h][r] = fc2w[(h * 64 + obase + r) * 8 + col];

        f32x4 acc3[2][4];
        #pragma unroll
        for (int h = 0; h < 2; ++h)
            #pragma unroll
            for (int nt = 0; nt < 4; ++nt) acc3[h][nt] = (f32x4){0.f, 0.f, 0.f, 0.f};
        #pragma unroll
        for (int ks = 0; ks < 2; ++ks) {
            const int k = ks * 32 + quad * 8;
            const f16x8 a0 = *(const f16x8*)&w3f16[(wv * 16 + n16) * 64 + k];
            const f16x8 a1 = *(const f16x8*)&w3f16[(64 + wv * 16 + n16) * 64 + k];
            #pragma unroll
            for (int nt = 0; nt < 4; ++nt) {
                const f16x8 bf = *(const f16x8*)&u.cv.h2[nt * 16 + n16][k];
                acc3[0][nt] = __builtin_amdgcn_mfma_f32_16x16x32_f16(a0, bf, acc3[0][nt], 0, 0, 0);
                acc3[1][nt] = __builtin_amdgcn_mfma_f32_16x16x32_f16(a1, bf, acc3[1][nt], 0, 0, 0);
            }
        }
        float part[4] = {0.f, 0.f, 0.f, 0.f};
        #pragma unroll
        for (int h = 0; h < 2; ++h) {
            const float4 bq = *(const float4*)&b3f[h * 64 + obase];
            const float bqa[4] = {bq.x, bq.y, bq.z, bq.w};
            #pragma unroll
            for (int nt = 0; nt < 4; ++nt) {
                const int n = nt * 16 + n16;
                const f16x4 rx = *(const f16x4*)&xp[n][h * 64 + obase];
                float p = 0.f;
                #pragma unroll
                for (int r = 0; r < 4; ++r) {
                    float v = acc3[h][nt][r] + bqa[r] + (float)rx[r];
                    v = fmaxf(v, 0.f);
                    p += v * fcv[h][r];
                }
                part[nt] += p;
            }
        }
        #pragma unroll
        for (int off_i = 0; off_i < 5; ++off_i) {
            const int off = (int[]){1, 2, 4, 16, 32}[off_i];
            part[0] += __shfl_xor(part[0], off, 64);
            part[1] += __shfl_xor(part[1], off, 64);
            part[2] += __shfl_xor(part[2], off, 64);
            part[3] += __shfl_xor(part[3], off, 64);
        }
        if ((lane & 55) == 0) {          // lanes 0 and 8
            const int par = (lane >> 3) & 1;
            wsum[wv][0 + par] = part[0];
            wsum[wv][2 + par] = part[1];
            wsum[wv][4 + par] = part[2];
            wsum[wv][6 + par] = part[3];
        }
    }
    __syncthreads();   // B5

    if (tid < 8) {
        const float s = wsum[0][tid] + wsum[1][tid] + wsum[2][tid] + wsum[3][tid];
        out[img * 2048 + mblk * 8 + tid] = s + fc2b[0];
    }
}

// ---------------------------------------------------------------------------
extern "C" void kernel_launch(void* const* d_in, const int* in_sizes, int n_in,
                              void* d_out, int out_size, void* d_ws, size_t ws_size,
                              hipStream_t stream) {
    const float* feature = (const float*)d_in[0];
    const float* lines   = (const float*)d_in[1];
    const float* fc1_w   = (const float*)d_in[2];
    const float* fc1_b   = (const float*)d_in[3];
    const float* bn1g    = (const float*)d_in[4];
    const float* bn1b    = (const float*)d_in[5];
    const float* bn1m    = (const float*)d_in[6];
    const float* bn1v    = (const float*)d_in[7];
    const float* w1      = (const float*)d_in[8];
    const float* b1      = (const float*)d_in[9];
    const float* bn2g    = (const float*)d_in[10];
    const float* bn2b    = (const float*)d_in[11];
    const float* bn2m    = (const float*)d_in[12];
    const float* bn2v    = (const float*)d_in[13];
    const float* w2      = (const float*)d_in[14];
    const float* b2      = (const float*)d_in[15];
    const float* bn3g    = (const float*)d_in[16];
    const float* bn3b    = (const float*)d_in[17];
    const float* bn3m    = (const float*)d_in[18];
    const float* bn3v    = (const float*)d_in[19];
    const float* w3      = (const float*)d_in[20];
    const float* b3      = (const float*)d_in[21];
    const float* fc2w    = (const float*)d_in[22];
    const float* fc2b    = (const float*)d_in[23];

    f16* xmap = (f16*)d_ws;                                      // 32 MiB
    f16* wsp  = (f16*)((char*)d_ws + (size_t)32 * 1024 * 1024);  // 120 KiB

    wprep_kernel<<<240, 256, 0, stream>>>(fc1_w, w1, w2, w3, wsp);
    fc1_mfma<<<256, 1024, 0, stream>>>(feature, wsp, fc1_b, xmap);
    loi_kernel<<<2048, 256, 0, stream>>>(xmap, lines, wsp,
                                         bn1g, bn1b, bn1m, bn1v, b1,
                                         bn2g, bn2b, bn2m, bn2v, b2,
                                         bn3g, bn3b, bn3m, bn3v, b3,
                                         fc2w, fc2b, (float*)d_out);
}